// Round 2
// baseline (1906.793 us; speedup 1.0000x reference)
//
#include <hip/hip_runtime.h>
#include <hip/hip_bf16.h>

// DynamicJKGCN on MI355X — round 2: robust correctness.
//  * Runtime dtype sniff (bf16 vs fp32 inputs/output) — branch on a flag in ws.
//  * Workspace cut to ~51.6 MB (two N*128 fp32 buffers); JK never materialized:
//    out accumulates w_l * (h_l @ Wfc) per layer directly in d_out.
//
// Schedule (A,B are N*128 fp32 in ws):
//   deg/odeg atomics -> dinv=rsqrt(deg); jkw=softmax(jk_weights)
//   L0: A=x@W1 ; B=0; agg A->B ; B=h0pre=relu(B+dinv^2*A+b1)
//       A=0; nsum B->A ; A=h0=(odeg>0? A/odeg : B) ; out  = w0*(A@Wfc)
//   L1: B=A@W2 ; A=0; agg B->A ; A=h1=relu(A+dinv^2*B+b2) ; out += w1*(A@Wfc)
//   L2: B=A@W3 ; A=0; agg B->A ; A=h2=relu(A+dinv^2*B+b3) ; out += w2*(A@Wfc)+bfc

#define H_FEATS 128

__device__ __forceinline__ float dload(const void* p, size_t i, int isbf) {
    return isbf ? __bfloat162float(((const __hip_bfloat16*)p)[i])
                : ((const float*)p)[i];
}

// ---------------- dtype sniff ----------------
// bf16 data: low 16 bits of each 32b word is a bf16 value ~N(0,1) -> exponent
// byte in [0x60,0x8F] essentially always. fp32 data: low 16 bits are uniform
// mantissa bits -> ~18.75% hit rate. 4096 samples separates cleanly.
__global__ __launch_bounds__(256) void sniff_dtype(const unsigned int* __restrict__ x,
                                                   int* __restrict__ flag) {
    __shared__ int cnt[256];
    int t = threadIdx.x;
    int c = 0;
    for (int i = 0; i < 16; i++) {
        unsigned int w = x[t * 16 + i];
        unsigned int e = (w >> 7) & 0xFFu;   // exponent byte of low-half bf16
        c += (e >= 0x60u && e <= 0x8Fu) ? 1 : 0;
    }
    cnt[t] = c;
    __syncthreads();
    for (int s = 128; s > 0; s >>= 1) {
        if (t < s) cnt[t] += cnt[t + s];
        __syncthreads();
    }
    if (t == 0) *flag = (cnt[0] > 3000) ? 1 : 0;
}

// ---------------- degree kernels ----------------
__global__ __launch_bounds__(256) void init_deg(float* deg, float* odeg, int N) {
    int i = blockIdx.x * 256 + threadIdx.x;
    if (i < N) { deg[i] = 1.0f; odeg[i] = 0.0f; }  // deg starts at 1: self-loop
}

__global__ __launch_bounds__(256) void count_deg(const int* __restrict__ row, const int* __restrict__ col,
                                                 float* deg, float* odeg, int E) {
    int e = blockIdx.x * 256 + threadIdx.x;
    if (e < E) {
        atomicAdd(&deg[col[e]], 1.0f);
        atomicAdd(&odeg[row[e]], 1.0f);
    }
}

__global__ __launch_bounds__(256) void deg_to_dinv(float* deg, int N) {
    int i = blockIdx.x * 256 + threadIdx.x;
    if (i < N) deg[i] = rsqrtf(deg[i]);
}

// meta[0] (as int) = dtype flag ; meta[8..10] = softmax(jk_weights)
__global__ void compute_jkw(const void* __restrict__ jkwb, float* __restrict__ meta) {
    if (threadIdx.x == 0) {
        int isbf = ((const int*)meta)[0];
        float w0 = dload(jkwb, 0, isbf);
        float w1 = dload(jkwb, 1, isbf);
        float w2 = dload(jkwb, 2, isbf);
        float m = fmaxf(w0, fmaxf(w1, w2));
        float e0 = expf(w0 - m), e1 = expf(w1 - m), e2 = expf(w2 - m);
        float s = e0 + e1 + e2;
        meta[8] = e0 / s; meta[9] = e1 / s; meta[10] = e2 / s;
    }
}

// ---------------- GEMM: C[N x 128] = X[N x K] @ W[K x 128] ----------------
// block=256, tile 64x128, BK=16, micro-tile 4x8.
template <int K, bool XIN>
__global__ __launch_bounds__(256) void gemm128(const void* __restrict__ Xv,
                                               const void* __restrict__ Wv,
                                               float* __restrict__ C,
                                               const int* __restrict__ flagp, int N) {
    constexpr int BM = 64, BK = 16, BN = 128, TN = 8, TX = BN / TN;  // TX=16
    __shared__ float Xs[BK][BM + 4];
    __shared__ float Ws[BK][BN];
    const int isbf = *flagp;
    const float* Xf = (const float*)Xv;

    const int tid = threadIdx.x;
    const int tx = tid % TX;
    const int ty = tid / TX;
    const int rowBase = blockIdx.x * BM;

    float acc[4][TN] = {};
    const int lk = tid % BK;
    const int lr0 = tid / BK;

    for (int kb = 0; kb < K; kb += BK) {
#pragma unroll
        for (int i = 0; i < 4; i++) {
            int r = lr0 + i * 16;
            int gr = rowBase + r;
            float v = 0.0f;
            if (gr < N) {
                size_t idx = (size_t)gr * K + kb + lk;
                v = XIN ? dload(Xv, idx, isbf) : Xf[idx];
            }
            Xs[lk][r] = v;
        }
#pragma unroll
        for (int i = 0; i < 8; i++) {
            int idx = i * 256 + tid;
            int k = idx >> 7, c = idx & 127;
            Ws[k][c] = dload(Wv, (size_t)(kb + k) * BN + c, isbf);
        }
        __syncthreads();
#pragma unroll
        for (int k = 0; k < BK; k++) {
            float4 a = *(const float4*)&Xs[k][ty * 4];
            float av[4] = {a.x, a.y, a.z, a.w};
            float4 b0 = *(const float4*)&Ws[k][tx * TN];
            float4 b1 = *(const float4*)&Ws[k][tx * TN + 4];
            float bv[8] = {b0.x, b0.y, b0.z, b0.w, b1.x, b1.y, b1.z, b1.w};
#pragma unroll
            for (int i = 0; i < 4; i++)
#pragma unroll
                for (int j = 0; j < TN; j++) acc[i][j] = fmaf(av[i], bv[j], acc[i][j]);
        }
        __syncthreads();
    }
#pragma unroll
    for (int i = 0; i < 4; i++) {
        int gr = rowBase + ty * 4 + i;
        if (gr < N) {
#pragma unroll
            for (int j = 0; j < TN; j++) C[(size_t)gr * BN + tx * TN + j] = acc[i][j];
        }
    }
}

// out[N x 64] (+)= scale * (H[N x 128] @ Wfc)  [+ bfc on LAST]; dtype per flag.
template <bool FIRST, bool LAST>
__global__ __launch_bounds__(256) void fc_accum(const float* __restrict__ Hm,
                                                const void* __restrict__ Wv,
                                                const void* __restrict__ bv,
                                                void* __restrict__ Outv,
                                                const float* __restrict__ meta,
                                                int widx, int N) {
    constexpr int BM = 64, BK = 16, BN = 64, TN = 4, TX = BN / TN, K = 128;
    __shared__ float Xs[BK][BM + 4];
    __shared__ float Ws[BK][BN];
    const int isbf = ((const int*)meta)[0];
    const float scale = meta[8 + widx];

    const int tid = threadIdx.x;
    const int tx = tid % TX;
    const int ty = tid / TX;
    const int rowBase = blockIdx.x * BM;

    float acc[4][TN] = {};
    const int lk = tid % BK;
    const int lr0 = tid / BK;

    for (int kb = 0; kb < K; kb += BK) {
#pragma unroll
        for (int i = 0; i < 4; i++) {
            int r = lr0 + i * 16;
            int gr = rowBase + r;
            float v = 0.0f;
            if (gr < N) v = Hm[(size_t)gr * K + kb + lk];
            Xs[lk][r] = v;
        }
#pragma unroll
        for (int i = 0; i < 4; i++) {
            int idx = i * 256 + tid;
            int k = idx >> 6, c = idx & 63;
            Ws[k][c] = dload(Wv, (size_t)(kb + k) * BN + c, isbf);
        }
        __syncthreads();
#pragma unroll
        for (int k = 0; k < BK; k++) {
            float4 a = *(const float4*)&Xs[k][ty * 4];
            float av[4] = {a.x, a.y, a.z, a.w};
            float4 bb = *(const float4*)&Ws[k][tx * TN];
            float bvv[4] = {bb.x, bb.y, bb.z, bb.w};
#pragma unroll
            for (int i = 0; i < 4; i++)
#pragma unroll
                for (int j = 0; j < TN; j++) acc[i][j] = fmaf(av[i], bvv[j], acc[i][j]);
        }
        __syncthreads();
    }
    __hip_bfloat16* ob = (__hip_bfloat16*)Outv;
    float* of = (float*)Outv;
#pragma unroll
    for (int i = 0; i < 4; i++) {
        int gr = rowBase + ty * 4 + i;
        if (gr < N) {
#pragma unroll
            for (int j = 0; j < TN; j++) {
                int c = tx * TN + j;
                size_t o = (size_t)gr * BN + c;
                float v = scale * acc[i][j];
                if (!FIRST) v += isbf ? __bfloat162float(ob[o]) : of[o];
                if (LAST) v += dload(bv, c, isbf);
                if (isbf) ob[o] = __float2bfloat16(v); else of[o] = v;
            }
        }
    }
}

// ---------------- edge aggregation (atomic scatter) ----------------
__global__ __launch_bounds__(256) void agg_edges(const int* __restrict__ row, const int* __restrict__ col,
                                                 const float* __restrict__ dinv,
                                                 const float* __restrict__ H,
                                                 float* __restrict__ agg, int E) {
    int e = blockIdx.x * 2 + (threadIdx.x >> 7);
    if (e >= E) return;
    int j = threadIdx.x & 127;
    int s = row[e], d = col[e];
    float w = dinv[s] * dinv[d];
    atomicAdd(&agg[(size_t)d * H_FEATS + j], w * H[(size_t)s * H_FEATS + j]);
}

__global__ __launch_bounds__(256) void mean_edges(const int* __restrict__ row, const int* __restrict__ col,
                                                  const float* __restrict__ h0pre,
                                                  float* __restrict__ nsum, int E) {
    int e = blockIdx.x * 2 + (threadIdx.x >> 7);
    if (e >= E) return;
    int j = threadIdx.x & 127;
    int r = row[e], c = col[e];
    atomicAdd(&nsum[(size_t)r * H_FEATS + j], h0pre[(size_t)c * H_FEATS + j]);
}

// hout = relu(agg + dinv^2 * H + b)   (hout may alias agg)
__global__ __launch_bounds__(256) void finalize_layer(const float* __restrict__ agg,
                                                      const float* __restrict__ H,
                                                      const float* __restrict__ dinv,
                                                      const void* __restrict__ bv,
                                                      float* __restrict__ hout,
                                                      const int* __restrict__ flagp, int NH) {
    int idx = blockIdx.x * 256 + threadIdx.x;
    if (idx >= NH) return;
    int isbf = *flagp;
    int v = idx >> 7, j = idx & 127;
    float di = dinv[v];
    float h = fmaf(di * di, H[idx], agg[idx]) + dload(bv, j, isbf);
    hout[idx] = fmaxf(h, 0.0f);
}

// h0 = odeg>0 ? nsum/odeg : h0pre   (h0 aliases nsum)
__global__ __launch_bounds__(256) void finalize_mean(const float* __restrict__ nsum,
                                                     const float* __restrict__ h0pre,
                                                     const float* __restrict__ odeg,
                                                     float* __restrict__ h0, int NH) {
    int idx = blockIdx.x * 256 + threadIdx.x;
    if (idx >= NH) return;
    int v = idx >> 7;
    float od = odeg[v];
    h0[idx] = (od > 0.0f) ? (nsum[idx] / od) : h0pre[idx];
}

extern "C" void kernel_launch(void* const* d_in, const int* in_sizes, int n_in,
                              void* d_out, int out_size, void* d_ws, size_t ws_size,
                              hipStream_t stream) {
    const void* x   = d_in[0];
    const int*  ei  = (const int*)d_in[1];
    const void* W1  = d_in[2];
    const void* b1  = d_in[3];
    const void* W2  = d_in[4];
    const void* b2  = d_in[5];
    const void* W3  = d_in[6];
    const void* b3  = d_in[7];
    const void* jkb = d_in[8];
    const void* Wfc = d_in[9];
    const void* bfc = d_in[10];

    const int IN = 256;
    const int N = in_sizes[0] / IN;          // 50000
    const int E = in_sizes[1] / 2;           // 800000
    const int NH = N * H_FEATS;

    // ws layout (fp32 units): meta[256] | dinv[N] | odeg[N] | pad | A[NH] | B[NH]
    float* ws = (float*)d_ws;
    float* meta = ws;                         // meta[0]=dtype flag (int), meta[8..10]=jkw
    float* dinv = ws + 256;
    float* odeg = dinv + N;
    size_t offA = ((size_t)(256 + 2 * N) + 63) & ~(size_t)63;
    float* A = ws + offA;
    float* B = A + NH;
    // required: (offA + 2*NH)*4 ≈ 51.6 MB  (ws_size assumed >= this)

    const int* row = ei;
    const int* col = ei + E;
    const int* flag = (const int*)meta;

    dim3 blk(256);
    int gN = (N + 255) / 256;
    int gE = (E + 255) / 256;
    int gE2 = (E + 1) / 2;
    int gNH = (NH + 255) / 256;
    int gGemm = (N + 63) / 64;

    sniff_dtype<<<1, blk, 0, stream>>>((const unsigned int*)x, (int*)meta);
    init_deg<<<gN, blk, 0, stream>>>(dinv, odeg, N);
    count_deg<<<gE, blk, 0, stream>>>(row, col, dinv, odeg, E);
    deg_to_dinv<<<gN, blk, 0, stream>>>(dinv, N);
    compute_jkw<<<1, 64, 0, stream>>>(jkb, meta);

    // ---- layer 0 ----
    gemm128<256, true><<<gGemm, blk, 0, stream>>>(x, W1, A, flag, N);
    hipMemsetAsync(B, 0, (size_t)NH * 4, stream);
    agg_edges<<<gE2, blk, 0, stream>>>(row, col, dinv, A, B, E);
    finalize_layer<<<gNH, blk, 0, stream>>>(B, A, dinv, b1, B, flag, NH);   // B = h0pre
    hipMemsetAsync(A, 0, (size_t)NH * 4, stream);
    mean_edges<<<gE2, blk, 0, stream>>>(row, col, B, A, E);                 // A = nsum
    finalize_mean<<<gNH, blk, 0, stream>>>(A, B, odeg, A, NH);              // A = h0
    fc_accum<true, false><<<gGemm, blk, 0, stream>>>(A, Wfc, bfc, d_out, meta, 0, N);

    // ---- layer 1 (EMA is forward-identity) ----
    gemm128<128, false><<<gGemm, blk, 0, stream>>>(A, W2, B, flag, N);      // B = H1
    hipMemsetAsync(A, 0, (size_t)NH * 4, stream);
    agg_edges<<<gE2, blk, 0, stream>>>(row, col, dinv, B, A, E);
    finalize_layer<<<gNH, blk, 0, stream>>>(A, B, dinv, b2, A, flag, NH);   // A = h1
    fc_accum<false, false><<<gGemm, blk, 0, stream>>>(A, Wfc, bfc, d_out, meta, 1, N);

    // ---- layer 2 ----
    gemm128<128, false><<<gGemm, blk, 0, stream>>>(A, W3, B, flag, N);      // B = H2
    hipMemsetAsync(A, 0, (size_t)NH * 4, stream);
    agg_edges<<<gE2, blk, 0, stream>>>(row, col, dinv, B, A, E);
    finalize_layer<<<gNH, blk, 0, stream>>>(A, B, dinv, b3, A, flag, NH);   // A = h2
    fc_accum<false, true><<<gGemm, blk, 0, stream>>>(A, Wfc, bfc, d_out, meta, 2, N);
}

// Round 3
// 1010.128 us; speedup vs baseline: 1.8877x; 1.8877x over previous
//
#include <hip/hip_runtime.h>
#include <hip/hip_bf16.h>

// DynamicJKGCN on MI355X — round 3: CSR gather aggregation (kill the atomics).
// Round-2 profile: 4 edge passes x 345us, WRITE_SIZE=400MB each (every fp32
// atomicAdd goes to fabric). Fix: device-built CSR + one-wave-per-node gather
// with fused self-loop+bias+relu (agg) and mean+fallback (mean pass).
// Runtime tiering on ws_size: A=full CSR (~59MB), B=CSR-col+atomic mean
// (~55.4MB), C=round-2 atomic path (~51.6MB, known good).

#define H_FEATS 128

__device__ __forceinline__ float dload(const void* p, size_t i, int isbf) {
    return isbf ? __bfloat162float(((const __hip_bfloat16*)p)[i])
                : ((const float*)p)[i];
}

// ---------------- dtype sniff ----------------
__global__ __launch_bounds__(256) void sniff_dtype(const unsigned int* __restrict__ x,
                                                   int* __restrict__ flag) {
    __shared__ int cnt[256];
    int t = threadIdx.x;
    int c = 0;
    for (int i = 0; i < 16; i++) {
        unsigned int w = x[t * 16 + i];
        unsigned int e = (w >> 7) & 0xFFu;
        c += (e >= 0x60u && e <= 0x8Fu) ? 1 : 0;
    }
    cnt[t] = c;
    __syncthreads();
    for (int s = 128; s > 0; s >>= 1) {
        if (t < s) cnt[t] += cnt[t + s];
        __syncthreads();
    }
    if (t == 0) *flag = (cnt[0] > 3000) ? 1 : 0;
}

// meta[0]=dtype flag (int); meta[8..10]=softmax(jk_weights)
__global__ void compute_jkw(const void* __restrict__ jkwb, float* __restrict__ meta) {
    if (threadIdx.x == 0) {
        int isbf = ((const int*)meta)[0];
        float w0 = dload(jkwb, 0, isbf);
        float w1 = dload(jkwb, 1, isbf);
        float w2 = dload(jkwb, 2, isbf);
        float m = fmaxf(w0, fmaxf(w1, w2));
        float e0 = expf(w0 - m), e1 = expf(w1 - m), e2 = expf(w2 - m);
        float s = e0 + e1 + e2;
        meta[8] = e0 / s; meta[9] = e1 / s; meta[10] = e2 / s;
    }
}

// ---------------- CSR build ----------------
__global__ __launch_bounds__(256) void histo(const int* __restrict__ row, const int* __restrict__ col,
                                             int* __restrict__ cntc, int* __restrict__ cntr, int E) {
    int e = blockIdx.x * 256 + threadIdx.x;
    if (e < E) {
        atomicAdd(&cntc[col[e]], 1);
        atomicAdd(&cntr[row[e]], 1);
    }
}

__global__ __launch_bounds__(256) void dinv_from_cnt(const int* __restrict__ cntc,
                                                     float* __restrict__ dinv, int N) {
    int i = blockIdx.x * 256 + threadIdx.x;
    if (i < N) dinv[i] = rsqrtf(1.0f + (float)cntc[i]);  // +1 self-loop
}

// grid=2: block 0 scans (c0->o0,u0), block 1 scans (c1->o1,u1). off is exclusive, off[N]=total.
__global__ __launch_bounds__(1024) void scan2(const int* __restrict__ c0, int* __restrict__ o0, int* __restrict__ u0,
                                              const int* __restrict__ c1, int* __restrict__ o1, int* __restrict__ u1,
                                              int N) {
    const int* cnt = blockIdx.x ? c1 : c0;
    int* off = blockIdx.x ? o1 : o0;
    int* cur = blockIdx.x ? u1 : u0;
    __shared__ int part[1024];
    int t = threadIdx.x;
    int chunk = (N + 1023) / 1024;
    int beg = t * chunk;
    int end = beg + chunk; if (end > N) end = N;
    if (beg > N) beg = N;
    int s = 0;
    for (int i = beg; i < end; i++) s += cnt[i];
    part[t] = s;
    __syncthreads();
    for (int d = 1; d < 1024; d <<= 1) {
        int v = (t >= d) ? part[t - d] : 0;
        __syncthreads();
        part[t] += v;
        __syncthreads();
    }
    int base = (t == 0) ? 0 : part[t - 1];
    for (int i = beg; i < end; i++) {
        off[i] = base; cur[i] = base; base += cnt[i];
    }
    if (end == N && beg < N) off[N] = base;
}

__global__ __launch_bounds__(256) void scatter2(const int* __restrict__ row, const int* __restrict__ col,
                                                int* __restrict__ curc, int* __restrict__ curr,
                                                int* __restrict__ ecol, int* __restrict__ erow,
                                                int E, int doRow) {
    int e = blockIdx.x * 256 + threadIdx.x;
    if (e >= E) return;
    int s = row[e], d = col[e];
    int p = atomicAdd(&curc[d], 1);
    ecol[p] = s;
    if (doRow) {
        int q = atomicAdd(&curr[s], 1);
        erow[q] = d;
    }
}

// ---------------- gather aggregation (one wave per node) ----------------
// hout[d] = relu( sum_{s in N_in(d)} dinv[s]dinv[d] H[s] + dinv[d]^2 H[d] + b )
__global__ __launch_bounds__(256) void agg_gather(const int* __restrict__ off,
                                                  const int* __restrict__ idx,
                                                  const float* __restrict__ dinv,
                                                  const float* __restrict__ H,
                                                  const void* __restrict__ bv,
                                                  float* __restrict__ hout,
                                                  const int* __restrict__ flagp, int N) {
    int node = blockIdx.x * 4 + (threadIdx.x >> 6);
    if (node >= N) return;
    int lane = threadIdx.x & 63;
    int isbf = *flagp;
    int beg = off[node], end = off[node + 1];
    float dd = dinv[node];
    float2 hv = *(const float2*)&H[(size_t)node * H_FEATS + lane * 2];
    float2 acc;
    acc.x = dd * dd * hv.x;
    acc.y = dd * dd * hv.y;
    int s = (beg < end) ? idx[beg] : 0;
    for (int i = beg; i < end; i++) {
        int sn = (i + 1 < end) ? idx[i + 1] : 0;       // prefetch next src
        float w = dinv[s] * dd;
        float2 h2 = *(const float2*)&H[(size_t)s * H_FEATS + lane * 2];
        acc.x = fmaf(w, h2.x, acc.x);
        acc.y = fmaf(w, h2.y, acc.y);
        s = sn;
    }
    acc.x = fmaxf(acc.x + dload(bv, lane * 2, isbf), 0.0f);
    acc.y = fmaxf(acc.y + dload(bv, lane * 2 + 1, isbf), 0.0f);
    *(float2*)&hout[(size_t)node * H_FEATS + lane * 2] = acc;
}

// h0[r] = (odeg>0) ? mean_{c in N_out(r)} h0pre[c] : h0pre[r]
__global__ __launch_bounds__(256) void mean_gather(const int* __restrict__ off,
                                                   const int* __restrict__ idx,
                                                   const float* __restrict__ Hsrc,
                                                   float* __restrict__ hout, int N) {
    int node = blockIdx.x * 4 + (threadIdx.x >> 6);
    if (node >= N) return;
    int lane = threadIdx.x & 63;
    int beg = off[node], end = off[node + 1];
    float2 acc = {0.0f, 0.0f};
    int s = (beg < end) ? idx[beg] : 0;
    for (int i = beg; i < end; i++) {
        int sn = (i + 1 < end) ? idx[i + 1] : 0;
        float2 h2 = *(const float2*)&Hsrc[(size_t)s * H_FEATS + lane * 2];
        acc.x += h2.x; acc.y += h2.y;
        s = sn;
    }
    int cnt = end - beg;
    float2 res;
    if (cnt > 0) {
        float inv = 1.0f / (float)cnt;
        res.x = acc.x * inv; res.y = acc.y * inv;
    } else {
        res = *(const float2*)&Hsrc[(size_t)node * H_FEATS + lane * 2];
    }
    *(float2*)&hout[(size_t)node * H_FEATS + lane * 2] = res;
}

// ---------------- GEMMs (unchanged from round 2) ----------------
template <int K, bool XIN>
__global__ __launch_bounds__(256) void gemm128(const void* __restrict__ Xv,
                                               const void* __restrict__ Wv,
                                               float* __restrict__ C,
                                               const int* __restrict__ flagp, int N) {
    constexpr int BM = 64, BK = 16, BN = 128, TN = 8, TX = BN / TN;
    __shared__ float Xs[BK][BM + 4];
    __shared__ float Ws[BK][BN];
    const int isbf = *flagp;
    const float* Xf = (const float*)Xv;

    const int tid = threadIdx.x;
    const int tx = tid % TX;
    const int ty = tid / TX;
    const int rowBase = blockIdx.x * BM;

    float acc[4][TN] = {};
    const int lk = tid % BK;
    const int lr0 = tid / BK;

    for (int kb = 0; kb < K; kb += BK) {
#pragma unroll
        for (int i = 0; i < 4; i++) {
            int r = lr0 + i * 16;
            int gr = rowBase + r;
            float v = 0.0f;
            if (gr < N) {
                size_t idx = (size_t)gr * K + kb + lk;
                v = XIN ? dload(Xv, idx, isbf) : Xf[idx];
            }
            Xs[lk][r] = v;
        }
#pragma unroll
        for (int i = 0; i < 8; i++) {
            int idx = i * 256 + tid;
            int k = idx >> 7, c = idx & 127;
            Ws[k][c] = dload(Wv, (size_t)(kb + k) * BN + c, isbf);
        }
        __syncthreads();
#pragma unroll
        for (int k = 0; k < BK; k++) {
            float4 a = *(const float4*)&Xs[k][ty * 4];
            float av[4] = {a.x, a.y, a.z, a.w};
            float4 b0 = *(const float4*)&Ws[k][tx * TN];
            float4 b1 = *(const float4*)&Ws[k][tx * TN + 4];
            float bv[8] = {b0.x, b0.y, b0.z, b0.w, b1.x, b1.y, b1.z, b1.w};
#pragma unroll
            for (int i = 0; i < 4; i++)
#pragma unroll
                for (int j = 0; j < TN; j++) acc[i][j] = fmaf(av[i], bv[j], acc[i][j]);
        }
        __syncthreads();
    }
#pragma unroll
    for (int i = 0; i < 4; i++) {
        int gr = rowBase + ty * 4 + i;
        if (gr < N) {
#pragma unroll
            for (int j = 0; j < TN; j++) C[(size_t)gr * BN + tx * TN + j] = acc[i][j];
        }
    }
}

template <bool FIRST, bool LAST>
__global__ __launch_bounds__(256) void fc_accum(const float* __restrict__ Hm,
                                                const void* __restrict__ Wv,
                                                const void* __restrict__ bv,
                                                void* __restrict__ Outv,
                                                const float* __restrict__ meta,
                                                int widx, int N) {
    constexpr int BM = 64, BK = 16, BN = 64, TN = 4, TX = BN / TN, K = 128;
    __shared__ float Xs[BK][BM + 4];
    __shared__ float Ws[BK][BN];
    const int isbf = ((const int*)meta)[0];
    const float scale = meta[8 + widx];

    const int tid = threadIdx.x;
    const int tx = tid % TX;
    const int ty = tid / TX;
    const int rowBase = blockIdx.x * BM;

    float acc[4][TN] = {};
    const int lk = tid % BK;
    const int lr0 = tid / BK;

    for (int kb = 0; kb < K; kb += BK) {
#pragma unroll
        for (int i = 0; i < 4; i++) {
            int r = lr0 + i * 16;
            int gr = rowBase + r;
            float v = 0.0f;
            if (gr < N) v = Hm[(size_t)gr * K + kb + lk];
            Xs[lk][r] = v;
        }
#pragma unroll
        for (int i = 0; i < 4; i++) {
            int idx = i * 256 + tid;
            int k = idx >> 6, c = idx & 63;
            Ws[k][c] = dload(Wv, (size_t)(kb + k) * BN + c, isbf);
        }
        __syncthreads();
#pragma unroll
        for (int k = 0; k < BK; k++) {
            float4 a = *(const float4*)&Xs[k][ty * 4];
            float av[4] = {a.x, a.y, a.z, a.w};
            float4 bb = *(const float4*)&Ws[k][tx * TN];
            float bvv[4] = {bb.x, bb.y, bb.z, bb.w};
#pragma unroll
            for (int i = 0; i < 4; i++)
#pragma unroll
                for (int j = 0; j < TN; j++) acc[i][j] = fmaf(av[i], bvv[j], acc[i][j]);
        }
        __syncthreads();
    }
    __hip_bfloat16* ob = (__hip_bfloat16*)Outv;
    float* of = (float*)Outv;
#pragma unroll
    for (int i = 0; i < 4; i++) {
        int gr = rowBase + ty * 4 + i;
        if (gr < N) {
#pragma unroll
            for (int j = 0; j < TN; j++) {
                int c = tx * TN + j;
                size_t o = (size_t)gr * BN + c;
                float v = scale * acc[i][j];
                if (!FIRST) v += isbf ? __bfloat162float(ob[o]) : of[o];
                if (LAST) v += dload(bv, c, isbf);
                if (isbf) ob[o] = __float2bfloat16(v); else of[o] = v;
            }
        }
    }
}

// ---------------- atomic fallbacks (tier B / C) ----------------
__global__ __launch_bounds__(256) void init_deg(float* deg, float* odeg, int N) {
    int i = blockIdx.x * 256 + threadIdx.x;
    if (i < N) { deg[i] = 1.0f; odeg[i] = 0.0f; }
}

__global__ __launch_bounds__(256) void count_deg(const int* __restrict__ row, const int* __restrict__ col,
                                                 float* deg, float* odeg, int E) {
    int e = blockIdx.x * 256 + threadIdx.x;
    if (e < E) {
        atomicAdd(&deg[col[e]], 1.0f);
        atomicAdd(&odeg[row[e]], 1.0f);
    }
}

__global__ __launch_bounds__(256) void deg_to_dinv(float* deg, int N) {
    int i = blockIdx.x * 256 + threadIdx.x;
    if (i < N) deg[i] = rsqrtf(deg[i]);
}

__global__ __launch_bounds__(256) void agg_edges(const int* __restrict__ row, const int* __restrict__ col,
                                                 const float* __restrict__ dinv,
                                                 const float* __restrict__ H,
                                                 float* __restrict__ agg, int E) {
    int e = blockIdx.x * 2 + (threadIdx.x >> 7);
    if (e >= E) return;
    int j = threadIdx.x & 127;
    int s = row[e], d = col[e];
    float w = dinv[s] * dinv[d];
    atomicAdd(&agg[(size_t)d * H_FEATS + j], w * H[(size_t)s * H_FEATS + j]);
}

__global__ __launch_bounds__(256) void mean_edges(const int* __restrict__ row, const int* __restrict__ col,
                                                  const float* __restrict__ h0pre,
                                                  float* __restrict__ nsum, int E) {
    int e = blockIdx.x * 2 + (threadIdx.x >> 7);
    if (e >= E) return;
    int j = threadIdx.x & 127;
    int r = row[e], c = col[e];
    atomicAdd(&nsum[(size_t)r * H_FEATS + j], h0pre[(size_t)c * H_FEATS + j]);
}

__global__ __launch_bounds__(256) void finalize_layer(const float* __restrict__ agg,
                                                      const float* __restrict__ H,
                                                      const float* __restrict__ dinv,
                                                      const void* __restrict__ bv,
                                                      float* __restrict__ hout,
                                                      const int* __restrict__ flagp, int NH) {
    int idx = blockIdx.x * 256 + threadIdx.x;
    if (idx >= NH) return;
    int isbf = *flagp;
    int v = idx >> 7, j = idx & 127;
    float di = dinv[v];
    float h = fmaf(di * di, H[idx], agg[idx]) + dload(bv, j, isbf);
    hout[idx] = fmaxf(h, 0.0f);
}

// odeg from float array (tier C)
__global__ __launch_bounds__(256) void finalize_mean(const float* __restrict__ nsum,
                                                     const float* __restrict__ h0pre,
                                                     const float* __restrict__ odeg,
                                                     float* __restrict__ h0, int NH) {
    int idx = blockIdx.x * 256 + threadIdx.x;
    if (idx >= NH) return;
    int v = idx >> 7;
    float od = odeg[v];
    h0[idx] = (od > 0.0f) ? (nsum[idx] / od) : h0pre[idx];
}

// odeg from int count array (tier B)
__global__ __launch_bounds__(256) void finalize_mean_cnt(const float* __restrict__ nsum,
                                                         const float* __restrict__ h0pre,
                                                         const int* __restrict__ cntr,
                                                         float* __restrict__ h0, int NH) {
    int idx = blockIdx.x * 256 + threadIdx.x;
    if (idx >= NH) return;
    int v = idx >> 7;
    int od = cntr[v];
    h0[idx] = (od > 0) ? (nsum[idx] / (float)od) : h0pre[idx];
}

extern "C" void kernel_launch(void* const* d_in, const int* in_sizes, int n_in,
                              void* d_out, int out_size, void* d_ws, size_t ws_size,
                              hipStream_t stream) {
    const void* x   = d_in[0];
    const int*  ei  = (const int*)d_in[1];
    const void* W1  = d_in[2];
    const void* b1  = d_in[3];
    const void* W2  = d_in[4];
    const void* b2  = d_in[5];
    const void* W3  = d_in[6];
    const void* b3  = d_in[7];
    const void* jkb = d_in[8];
    const void* Wfc = d_in[9];
    const void* bfc = d_in[10];

    const int IN = 256;
    const int N = in_sizes[0] / IN;          // 50000
    const int E = in_sizes[1] / 2;           // 800000
    const int NH = N * H_FEATS;

    const int* row = ei;
    const int* col = ei + E;

    // ---- workspace layout (fp32 words) ----
    float* ws = (float*)d_ws;
    size_t o = 0;
    float* meta = ws + o;            o += 256;
    float* dinv = ws + o;            o += N;          // tier C: deg->dinv (float)
    int*   cntc = (int*)(ws + o);    o += N;          // tier C: odeg float lives here
    int*   cntr = (int*)(ws + o);    o += N;
    int*   coff = (int*)(ws + o);    o += N + 1;
    int*   curc = (int*)(ws + o);    o += N;
    int*   ecol = (int*)(ws + o);    o += E;
    size_t oB_small = o;                              // tier A extras follow
    int*   roff = (int*)(ws + o);    o += N + 1;
    int*   curr = (int*)(ws + o);    o += N;
    int*   erow = (int*)(ws + o);    o += E;
    size_t oA_full = o;

    auto alignup = [](size_t v) { return (v + 63) & ~(size_t)63; };
    size_t needA = alignup(oA_full) + 2 * (size_t)NH;
    size_t needB = alignup(oB_small) + 2 * (size_t)NH;
    size_t needC = alignup(256 + 2 * (size_t)N) + 2 * (size_t)NH;

    int tier;
    size_t hoff;
    if (ws_size >= needA * 4)      { tier = 0; hoff = alignup(oA_full); }
    else if (ws_size >= needB * 4) { tier = 1; hoff = alignup(oB_small); }
    else                           { tier = 2; hoff = alignup(256 + 2 * (size_t)N); }
    float* A = ws + hoff;
    float* B = A + NH;
    float* odegf = ws + 256 + N;     // tier C only (aliases cntc)
    const int* flag = (const int*)meta;

    dim3 blk(256);
    int gN = (N + 255) / 256;
    int gE = (E + 255) / 256;
    int gE2 = (E + 1) / 2;
    int gNH = (NH + 255) / 256;
    int gGemm = (N + 63) / 64;
    int gNode = (N + 3) / 4;

    sniff_dtype<<<1, blk, 0, stream>>>((const unsigned int*)x, (int*)meta);
    compute_jkw<<<1, 64, 0, stream>>>(jkb, meta);

    if (tier < 2) {
        // ---- CSR build ----
        hipMemsetAsync(cntc, 0, 2 * (size_t)N * 4, stream);   // cntc + cntr adjacent
        histo<<<gE, blk, 0, stream>>>(row, col, cntc, cntr, E);
        dinv_from_cnt<<<gN, blk, 0, stream>>>(cntc, dinv, N);
        if (tier == 0) {
            scan2<<<2, 1024, 0, stream>>>(cntc, coff, curc, cntr, roff, curr, N);
            scatter2<<<gE, blk, 0, stream>>>(row, col, curc, curr, ecol, erow, E, 1);
        } else {
            scan2<<<1, 1024, 0, stream>>>(cntc, coff, curc, cntc, coff, curc, N);
            scatter2<<<gE, blk, 0, stream>>>(row, col, curc, curc, ecol, ecol, E, 0);
        }

        // ---- layer 0 ----
        gemm128<256, true><<<gGemm, blk, 0, stream>>>(x, W1, A, flag, N);
        agg_gather<<<gNode, blk, 0, stream>>>(coff, ecol, dinv, A, b1, B, flag, N);   // B=h0pre
        if (tier == 0) {
            mean_gather<<<gNode, blk, 0, stream>>>(roff, erow, B, A, N);              // A=h0
        } else {
            hipMemsetAsync(A, 0, (size_t)NH * 4, stream);
            mean_edges<<<gE2, blk, 0, stream>>>(row, col, B, A, E);
            finalize_mean_cnt<<<gNH, blk, 0, stream>>>(A, B, cntr, A, NH);
        }
        fc_accum<true, false><<<gGemm, blk, 0, stream>>>(A, Wfc, bfc, d_out, meta, 0, N);

        // ---- layer 1 ----
        gemm128<128, false><<<gGemm, blk, 0, stream>>>(A, W2, B, flag, N);
        agg_gather<<<gNode, blk, 0, stream>>>(coff, ecol, dinv, B, b2, A, flag, N);   // A=h1
        fc_accum<false, false><<<gGemm, blk, 0, stream>>>(A, Wfc, bfc, d_out, meta, 1, N);

        // ---- layer 2 ----
        gemm128<128, false><<<gGemm, blk, 0, stream>>>(A, W3, B, flag, N);
        agg_gather<<<gNode, blk, 0, stream>>>(coff, ecol, dinv, B, b3, A, flag, N);   // A=h2
        fc_accum<false, true><<<gGemm, blk, 0, stream>>>(A, Wfc, bfc, d_out, meta, 2, N);
    } else {
        // ---- tier C: round-2 atomic path ----
        init_deg<<<gN, blk, 0, stream>>>(dinv, odegf, N);
        count_deg<<<gE, blk, 0, stream>>>(row, col, dinv, odegf, E);
        deg_to_dinv<<<gN, blk, 0, stream>>>(dinv, N);

        gemm128<256, true><<<gGemm, blk, 0, stream>>>(x, W1, A, flag, N);
        hipMemsetAsync(B, 0, (size_t)NH * 4, stream);
        agg_edges<<<gE2, blk, 0, stream>>>(row, col, dinv, A, B, E);
        finalize_layer<<<gNH, blk, 0, stream>>>(B, A, dinv, b1, B, flag, NH);
        hipMemsetAsync(A, 0, (size_t)NH * 4, stream);
        mean_edges<<<gE2, blk, 0, stream>>>(row, col, B, A, E);
        finalize_mean<<<gNH, blk, 0, stream>>>(A, B, odegf, A, NH);
        fc_accum<true, false><<<gGemm, blk, 0, stream>>>(A, Wfc, bfc, d_out, meta, 0, N);

        gemm128<128, false><<<gGemm, blk, 0, stream>>>(A, W2, B, flag, N);
        hipMemsetAsync(A, 0, (size_t)NH * 4, stream);
        agg_edges<<<gE2, blk, 0, stream>>>(row, col, dinv, B, A, E);
        finalize_layer<<<gNH, blk, 0, stream>>>(A, B, dinv, b2, A, flag, NH);
        fc_accum<false, false><<<gGemm, blk, 0, stream>>>(A, Wfc, bfc, d_out, meta, 1, N);

        gemm128<128, false><<<gGemm, blk, 0, stream>>>(A, W3, B, flag, N);
        hipMemsetAsync(A, 0, (size_t)NH * 4, stream);
        agg_edges<<<gE2, blk, 0, stream>>>(row, col, dinv, B, A, E);
        finalize_layer<<<gNH, blk, 0, stream>>>(A, B, dinv, b3, A, flag, NH);
        fc_accum<false, true><<<gGemm, blk, 0, stream>>>(A, Wfc, bfc, d_out, meta, 2, N);
    }
}

// Round 7
// 919.194 us; speedup vs baseline: 2.0744x; 1.0989x over previous
//
#include <hip/hip_runtime.h>
#include <hip/hip_bf16.h>

// DynamicJKGCN on MI355X — round 7: dtype-safe MFMA.
// Round-6 bisection: MFMA module NaN'd because it HARD-ASSUMED bf16 inputs;
// every flag-respecting round passed -> harness tensors are fp32 (flag=0).
// This round: MFMA fed from fp32 loads with in-register bf16 conversion.
// L0 runs two self-gating kernels (gemm128 iff flag==1, gemm_mfma_f32 iff
// flag==0) so either world passes and rocprof shows which ran. L1/L2 MFMA
// unconditional (input is fp32 ws buffer in both worlds). All else = round 3.

#define H_FEATS 128

typedef __attribute__((ext_vector_type(8))) short short8;   // 8 bf16 in 4 VGPRs
typedef __attribute__((ext_vector_type(4))) float float4v;  // 4 fp32 acc

__device__ __forceinline__ float dload(const void* p, size_t i, int isbf) {
    return isbf ? __bfloat162float(((const __hip_bfloat16*)p)[i])
                : ((const float*)p)[i];
}

// ---------------- dtype sniff ----------------
__global__ __launch_bounds__(256) void sniff_dtype(const unsigned int* __restrict__ x,
                                                   int* __restrict__ flag) {
    __shared__ int cnt[256];
    int t = threadIdx.x;
    int c = 0;
    for (int i = 0; i < 16; i++) {
        unsigned int w = x[t * 16 + i];
        unsigned int e = (w >> 7) & 0xFFu;
        c += (e >= 0x60u && e <= 0x8Fu) ? 1 : 0;
    }
    cnt[t] = c;
    __syncthreads();
    for (int s = 128; s > 0; s >>= 1) {
        if (t < s) cnt[t] += cnt[t + s];
        __syncthreads();
    }
    if (t == 0) *flag = (cnt[0] > 3000) ? 1 : 0;
}

// meta[0]=dtype flag (int); meta[8..10]=softmax(jk_weights)
__global__ void compute_jkw(const void* __restrict__ jkwb, float* __restrict__ meta) {
    if (threadIdx.x == 0) {
        int isbf = ((const int*)meta)[0];
        float w0 = dload(jkwb, 0, isbf);
        float w1 = dload(jkwb, 1, isbf);
        float w2 = dload(jkwb, 2, isbf);
        float m = fmaxf(w0, fmaxf(w1, w2));
        float e0 = expf(w0 - m), e1 = expf(w1 - m), e2 = expf(w2 - m);
        float s = e0 + e1 + e2;
        meta[8] = e0 / s; meta[9] = e1 / s; meta[10] = e2 / s;
    }
}

// ---------------- CSR build ----------------
__global__ __launch_bounds__(256) void histo(const int* __restrict__ row, const int* __restrict__ col,
                                             int* __restrict__ cntc, int* __restrict__ cntr, int E) {
    int e = blockIdx.x * 256 + threadIdx.x;
    if (e < E) {
        atomicAdd(&cntc[col[e]], 1);
        atomicAdd(&cntr[row[e]], 1);
    }
}

__global__ __launch_bounds__(256) void dinv_from_cnt(const int* __restrict__ cntc,
                                                     float* __restrict__ dinv, int N) {
    int i = blockIdx.x * 256 + threadIdx.x;
    if (i < N) dinv[i] = rsqrtf(1.0f + (float)cntc[i]);  // +1 self-loop
}

__global__ __launch_bounds__(1024) void scan2(const int* __restrict__ c0, int* __restrict__ o0, int* __restrict__ u0,
                                              const int* __restrict__ c1, int* __restrict__ o1, int* __restrict__ u1,
                                              int N) {
    const int* cnt = blockIdx.x ? c1 : c0;
    int* off = blockIdx.x ? o1 : o0;
    int* cur = blockIdx.x ? u1 : u0;
    __shared__ int part[1024];
    int t = threadIdx.x;
    int chunk = (N + 1023) / 1024;
    int beg = t * chunk;
    int end = beg + chunk; if (end > N) end = N;
    if (beg > N) beg = N;
    int s = 0;
    for (int i = beg; i < end; i++) s += cnt[i];
    part[t] = s;
    __syncthreads();
    for (int d = 1; d < 1024; d <<= 1) {
        int v = (t >= d) ? part[t - d] : 0;
        __syncthreads();
        part[t] += v;
        __syncthreads();
    }
    int base = (t == 0) ? 0 : part[t - 1];
    for (int i = beg; i < end; i++) {
        off[i] = base; cur[i] = base; base += cnt[i];
    }
    if (end == N && beg < N) off[N] = base;
}

__global__ __launch_bounds__(256) void scatter2(const int* __restrict__ row, const int* __restrict__ col,
                                                int* __restrict__ curc, int* __restrict__ curr,
                                                int* __restrict__ ecol, int* __restrict__ erow,
                                                int E, int doRow) {
    int e = blockIdx.x * 256 + threadIdx.x;
    if (e >= E) return;
    int s = row[e], d = col[e];
    int p = atomicAdd(&curc[d], 1);
    ecol[p] = s;
    if (doRow) {
        int q = atomicAdd(&curr[s], 1);
        erow[q] = d;
    }
}

// ---------------- W prepack for MFMA B-fragments (dtype-agnostic) ----------------
// Wp[((s*8 + t)*64 + lane)*8 + j] = bf16(W[s*32 + (lane>>4)*8 + j][t*16 + (lane&15)])
__global__ __launch_bounds__(256) void pack_w(const void* __restrict__ W,
                                              unsigned short* __restrict__ Wp,
                                              const int* __restrict__ flagp, int K) {
    int gid = blockIdx.x * 256 + threadIdx.x;
    int steps = K >> 5;
    if (gid >= steps * 8 * 64) return;
    int isbf = *flagp;
    int lane = gid & 63;
    int t = (gid >> 6) & 7;
    int s = gid >> 9;
    int krow = s * 32 + ((lane >> 4) << 3);
    int ncol = t * 16 + (lane & 15);
#pragma unroll
    for (int j = 0; j < 8; j++) {
        float v = dload(W, (size_t)(krow + j) * H_FEATS + ncol, isbf);
        Wp[(size_t)gid * 8 + j] = __bfloat16_as_ushort(__float2bfloat16(v));
    }
}

// ---------------- MFMA GEMM from fp32 input: C[M x 128] = X @ W ----------------
// GATED: body only when flag==0 (fp32 world). Ungated for L1/L2 (ws fp32 input).
template <int K, bool GATED>
__global__ __launch_bounds__(256) void gemm_mfma_f32(const float* __restrict__ X,
                                                     const unsigned short* __restrict__ Wp,
                                                     float* __restrict__ C,
                                                     const int* __restrict__ flagp, int M) {
    if (GATED && *flagp != 0) return;
    const int tid = threadIdx.x;
    const int wave = tid >> 6, lane = tid & 63;
    const int m16 = lane & 15, quad = lane >> 4;
    const int row = blockIdx.x * 64 + wave * 16 + m16;
    constexpr int STEPS = K / 32;

    float4v acc[8];
#pragma unroll
    for (int t = 0; t < 8; t++) acc[t] = (float4v){0.f, 0.f, 0.f, 0.f};

    const bool rowOK = row < M;
#pragma unroll
    for (int s = 0; s < STEPS; s++) {
        int k0 = s * 32 + quad * 8;
        short8 a = (short8)(short)0;
        if (rowOK) {
            const float* p = X + (size_t)row * K + k0;
            float4 f0 = *(const float4*)p;
            float4 f1 = *(const float4*)(p + 4);
            a[0] = (short)__bfloat16_as_ushort(__float2bfloat16(f0.x));
            a[1] = (short)__bfloat16_as_ushort(__float2bfloat16(f0.y));
            a[2] = (short)__bfloat16_as_ushort(__float2bfloat16(f0.z));
            a[3] = (short)__bfloat16_as_ushort(__float2bfloat16(f0.w));
            a[4] = (short)__bfloat16_as_ushort(__float2bfloat16(f1.x));
            a[5] = (short)__bfloat16_as_ushort(__float2bfloat16(f1.y));
            a[6] = (short)__bfloat16_as_ushort(__float2bfloat16(f1.z));
            a[7] = (short)__bfloat16_as_ushort(__float2bfloat16(f1.w));
        }
#pragma unroll
        for (int t = 0; t < 8; t++) {
            short8 b = *(const short8*)(Wp + ((size_t)(s * 8 + t) * 64 + lane) * 8);
            acc[t] = __builtin_amdgcn_mfma_f32_16x16x32_bf16(a, b, acc[t], 0, 0, 0);
        }
    }
    // C/D layout: col = t*16 + (lane&15), row = quad*4 + r
#pragma unroll
    for (int r = 0; r < 4; r++) {
        int gr = blockIdx.x * 64 + wave * 16 + quad * 4 + r;
        if (gr < M) {
#pragma unroll
            for (int t = 0; t < 8; t++)
                C[(size_t)gr * H_FEATS + t * 16 + m16] = acc[t][r];
        }
    }
}

// ---------------- gather aggregation (round-3 verbatim) ----------------
__global__ __launch_bounds__(256) void agg_gather(const int* __restrict__ off,
                                                  const int* __restrict__ idx,
                                                  const float* __restrict__ dinv,
                                                  const float* __restrict__ H,
                                                  const void* __restrict__ bv,
                                                  float* __restrict__ hout,
                                                  const int* __restrict__ flagp, int N) {
    int node = blockIdx.x * 4 + (threadIdx.x >> 6);
    if (node >= N) return;
    int lane = threadIdx.x & 63;
    int isbf = *flagp;
    int beg = off[node], end = off[node + 1];
    float dd = dinv[node];
    float2 hv = *(const float2*)&H[(size_t)node * H_FEATS + lane * 2];
    float2 acc;
    acc.x = dd * dd * hv.x;
    acc.y = dd * dd * hv.y;
    int s = (beg < end) ? idx[beg] : 0;
    for (int i = beg; i < end; i++) {
        int sn = (i + 1 < end) ? idx[i + 1] : 0;
        float w = dinv[s] * dd;
        float2 h2 = *(const float2*)&H[(size_t)s * H_FEATS + lane * 2];
        acc.x = fmaf(w, h2.x, acc.x);
        acc.y = fmaf(w, h2.y, acc.y);
        s = sn;
    }
    acc.x = fmaxf(acc.x + dload(bv, lane * 2, isbf), 0.0f);
    acc.y = fmaxf(acc.y + dload(bv, lane * 2 + 1, isbf), 0.0f);
    *(float2*)&hout[(size_t)node * H_FEATS + lane * 2] = acc;
}

__global__ __launch_bounds__(256) void mean_gather(const int* __restrict__ off,
                                                   const int* __restrict__ idx,
                                                   const float* __restrict__ Hsrc,
                                                   float* __restrict__ hout, int N) {
    int node = blockIdx.x * 4 + (threadIdx.x >> 6);
    if (node >= N) return;
    int lane = threadIdx.x & 63;
    int beg = off[node], end = off[node + 1];
    float2 acc = {0.0f, 0.0f};
    int s = (beg < end) ? idx[beg] : 0;
    for (int i = beg; i < end; i++) {
        int sn = (i + 1 < end) ? idx[i + 1] : 0;
        float2 h2 = *(const float2*)&Hsrc[(size_t)s * H_FEATS + lane * 2];
        acc.x += h2.x; acc.y += h2.y;
        s = sn;
    }
    int cnt = end - beg;
    float2 res;
    if (cnt > 0) {
        float inv = 1.0f / (float)cnt;
        res.x = acc.x * inv; res.y = acc.y * inv;
    } else {
        res = *(const float2*)&Hsrc[(size_t)node * H_FEATS + lane * 2];
    }
    *(float2*)&hout[(size_t)node * H_FEATS + lane * 2] = res;
}

// ---------------- fp32 GEMM (round-3 verbatim + optional bf16-only gate) ----------------
template <int K, bool XIN, bool GATEBF>
__global__ __launch_bounds__(256) void gemm128(const void* __restrict__ Xv,
                                               const void* __restrict__ Wv,
                                               float* __restrict__ C,
                                               const int* __restrict__ flagp, int N) {
    constexpr int BM = 64, BK = 16, BN = 128, TN = 8, TX = BN / TN;
    __shared__ float Xs[BK][BM + 4];
    __shared__ float Ws[BK][BN];
    const int isbf = *flagp;
    if (GATEBF && isbf != 1) return;
    const float* Xf = (const float*)Xv;

    const int tid = threadIdx.x;
    const int tx = tid % TX;
    const int ty = tid / TX;
    const int rowBase = blockIdx.x * BM;

    float acc[4][TN] = {};
    const int lk = tid % BK;
    const int lr0 = tid / BK;

    for (int kb = 0; kb < K; kb += BK) {
#pragma unroll
        for (int i = 0; i < 4; i++) {
            int r = lr0 + i * 16;
            int gr = rowBase + r;
            float v = 0.0f;
            if (gr < N) {
                size_t idx = (size_t)gr * K + kb + lk;
                v = XIN ? dload(Xv, idx, isbf) : Xf[idx];
            }
            Xs[lk][r] = v;
        }
#pragma unroll
        for (int i = 0; i < 8; i++) {
            int idx = i * 256 + tid;
            int k = idx >> 7, c = idx & 127;
            Ws[k][c] = dload(Wv, (size_t)(kb + k) * BN + c, isbf);
        }
        __syncthreads();
#pragma unroll
        for (int k = 0; k < BK; k++) {
            float4 a = *(const float4*)&Xs[k][ty * 4];
            float av[4] = {a.x, a.y, a.z, a.w};
            float4 b0 = *(const float4*)&Ws[k][tx * TN];
            float4 b1 = *(const float4*)&Ws[k][tx * TN + 4];
            float bv[8] = {b0.x, b0.y, b0.z, b0.w, b1.x, b1.y, b1.z, b1.w};
#pragma unroll
            for (int i = 0; i < 4; i++)
#pragma unroll
                for (int j = 0; j < TN; j++) acc[i][j] = fmaf(av[i], bv[j], acc[i][j]);
        }
        __syncthreads();
    }
#pragma unroll
    for (int i = 0; i < 4; i++) {
        int gr = rowBase + ty * 4 + i;
        if (gr < N) {
#pragma unroll
            for (int j = 0; j < TN; j++) C[(size_t)gr * BN + tx * TN + j] = acc[i][j];
        }
    }
}

template <bool FIRST, bool LAST>
__global__ __launch_bounds__(256) void fc_accum(const float* __restrict__ Hm,
                                                const void* __restrict__ Wv,
                                                const void* __restrict__ bv,
                                                void* __restrict__ Outv,
                                                const float* __restrict__ meta,
                                                int widx, int N) {
    constexpr int BM = 64, BK = 16, BN = 64, TN = 4, TX = BN / TN, K = 128;
    __shared__ float Xs[BK][BM + 4];
    __shared__ float Ws[BK][BN];
    const int isbf = ((const int*)meta)[0];
    const float scale = meta[8 + widx];

    const int tid = threadIdx.x;
    const int tx = tid % TX;
    const int ty = tid / TX;
    const int rowBase = blockIdx.x * BM;

    float acc[4][TN] = {};
    const int lk = tid % BK;
    const int lr0 = tid / BK;

    for (int kb = 0; kb < K; kb += BK) {
#pragma unroll
        for (int i = 0; i < 4; i++) {
            int r = lr0 + i * 16;
            int gr = rowBase + r;
            float v = 0.0f;
            if (gr < N) v = Hm[(size_t)gr * K + kb + lk];
            Xs[lk][r] = v;
        }
#pragma unroll
        for (int i = 0; i < 4; i++) {
            int idx = i * 256 + tid;
            int k = idx >> 6, c = idx & 63;
            Ws[k][c] = dload(Wv, (size_t)(kb + k) * BN + c, isbf);
        }
        __syncthreads();
#pragma unroll
        for (int k = 0; k < BK; k++) {
            float4 a = *(const float4*)&Xs[k][ty * 4];
            float av[4] = {a.x, a.y, a.z, a.w};
            float4 bb = *(const float4*)&Ws[k][tx * TN];
            float bvv[4] = {bb.x, bb.y, bb.z, bb.w};
#pragma unroll
            for (int i = 0; i < 4; i++)
#pragma unroll
                for (int j = 0; j < TN; j++) acc[i][j] = fmaf(av[i], bvv[j], acc[i][j]);
        }
        __syncthreads();
    }
    __hip_bfloat16* ob = (__hip_bfloat16*)Outv;
    float* of = (float*)Outv;
#pragma unroll
    for (int i = 0; i < 4; i++) {
        int gr = rowBase + ty * 4 + i;
        if (gr < N) {
#pragma unroll
            for (int j = 0; j < TN; j++) {
                int c = tx * TN + j;
                size_t o = (size_t)gr * BN + c;
                float v = scale * acc[i][j];
                if (!FIRST) v += isbf ? __bfloat162float(ob[o]) : of[o];
                if (LAST) v += dload(bv, c, isbf);
                if (isbf) ob[o] = __float2bfloat16(v); else of[o] = v;
            }
        }
    }
}

// ---------------- atomic fallbacks (tier B / C, round-3 verbatim) ----------------
__global__ __launch_bounds__(256) void init_deg(float* deg, float* odeg, int N) {
    int i = blockIdx.x * 256 + threadIdx.x;
    if (i < N) { deg[i] = 1.0f; odeg[i] = 0.0f; }
}
__global__ __launch_bounds__(256) void count_deg(const int* __restrict__ row, const int* __restrict__ col,
                                                 float* deg, float* odeg, int E) {
    int e = blockIdx.x * 256 + threadIdx.x;
    if (e < E) {
        atomicAdd(&deg[col[e]], 1.0f);
        atomicAdd(&odeg[row[e]], 1.0f);
    }
}
__global__ __launch_bounds__(256) void deg_to_dinv(float* deg, int N) {
    int i = blockIdx.x * 256 + threadIdx.x;
    if (i < N) deg[i] = rsqrtf(deg[i]);
}
__global__ __launch_bounds__(256) void agg_edges(const int* __restrict__ row, const int* __restrict__ col,
                                                 const float* __restrict__ dinv,
                                                 const float* __restrict__ H,
                                                 float* __restrict__ agg, int E) {
    int e = blockIdx.x * 2 + (threadIdx.x >> 7);
    if (e >= E) return;
    int j = threadIdx.x & 127;
    int s = row[e], d = col[e];
    float w = dinv[s] * dinv[d];
    atomicAdd(&agg[(size_t)d * H_FEATS + j], w * H[(size_t)s * H_FEATS + j]);
}
__global__ __launch_bounds__(256) void mean_edges(const int* __restrict__ row, const int* __restrict__ col,
                                                  const float* __restrict__ h0pre,
                                                  float* __restrict__ nsum, int E) {
    int e = blockIdx.x * 2 + (threadIdx.x >> 7);
    if (e >= E) return;
    int j = threadIdx.x & 127;
    int r = row[e], c = col[e];
    atomicAdd(&nsum[(size_t)r * H_FEATS + j], h0pre[(size_t)c * H_FEATS + j]);
}
__global__ __launch_bounds__(256) void finalize_layer(const float* __restrict__ agg,
                                                      const float* __restrict__ H,
                                                      const float* __restrict__ dinv,
                                                      const void* __restrict__ bv,
                                                      float* __restrict__ hout,
                                                      const int* __restrict__ flagp, int NH) {
    int idx = blockIdx.x * 256 + threadIdx.x;
    if (idx >= NH) return;
    int isbf = *flagp;
    int v = idx >> 7, j = idx & 127;
    float di = dinv[v];
    float h = fmaf(di * di, H[idx], agg[idx]) + dload(bv, j, isbf);
    hout[idx] = fmaxf(h, 0.0f);
}
__global__ __launch_bounds__(256) void finalize_mean(const float* __restrict__ nsum,
                                                     const float* __restrict__ h0pre,
                                                     const float* __restrict__ odeg,
                                                     float* __restrict__ h0, int NH) {
    int idx = blockIdx.x * 256 + threadIdx.x;
    if (idx >= NH) return;
    int v = idx >> 7;
    float od = odeg[v];
    h0[idx] = (od > 0.0f) ? (nsum[idx] / od) : h0pre[idx];
}
__global__ __launch_bounds__(256) void finalize_mean_cnt(const float* __restrict__ nsum,
                                                         const float* __restrict__ h0pre,
                                                         const int* __restrict__ cntr,
                                                         float* __restrict__ h0, int NH) {
    int idx = blockIdx.x * 256 + threadIdx.x;
    if (idx >= NH) return;
    int v = idx >> 7;
    int od = cntr[v];
    h0[idx] = (od > 0) ? (nsum[idx] / (float)od) : h0pre[idx];
}

extern "C" void kernel_launch(void* const* d_in, const int* in_sizes, int n_in,
                              void* d_out, int out_size, void* d_ws, size_t ws_size,
                              hipStream_t stream) {
    const void* x   = d_in[0];
    const int*  ei  = (const int*)d_in[1];
    const void* W1  = d_in[2];
    const void* b1  = d_in[3];
    const void* W2  = d_in[4];
    const void* b2  = d_in[5];
    const void* W3  = d_in[6];
    const void* b3  = d_in[7];
    const void* jkb = d_in[8];
    const void* Wfc = d_in[9];
    const void* bfc = d_in[10];

    const int IN = 256;
    const int N = in_sizes[0] / IN;          // 50000
    const int E = in_sizes[1] / 2;           // 800000
    const int NH = N * H_FEATS;

    const int* row = ei;
    const int* col = ei + E;

    // ---- workspace layout (fp32 words) — round-3 layout, Wp appended ----
    float* ws = (float*)d_ws;
    size_t o = 0;
    float* meta = ws + o;            o += 256;
    float* dinv = ws + o;            o += N;
    int*   cntc = (int*)(ws + o);    o += N;
    int*   cntr = (int*)(ws + o);    o += N;
    int*   coff = (int*)(ws + o);    o += N + 1;
    int*   curc = (int*)(ws + o);    o += N;
    int*   ecol = (int*)(ws + o);    o += E;
    size_t oB_small = o;
    int*   roff = (int*)(ws + o);    o += N + 1;
    int*   curr = (int*)(ws + o);    o += N;
    int*   erow = (int*)(ws + o);    o += E;
    size_t oA_full = o;

    auto alignup = [](size_t v) { return (v + 63) & ~(size_t)63; };
    const size_t WPW = 16384 + 8192 + 8192;                 // Wp region, fp32 words
    size_t needA = alignup(oA_full) + 2 * (size_t)NH + 64 + WPW;
    size_t needB = alignup(oB_small) + 2 * (size_t)NH + 64 + WPW;

    int tier;
    size_t hoff;
    if (ws_size >= needA * 4)      { tier = 0; hoff = alignup(oA_full); }
    else if (ws_size >= needB * 4) { tier = 1; hoff = alignup(oB_small); }
    else                           { tier = 2; hoff = alignup(256 + 2 * (size_t)N); }
    float* A = ws + hoff;
    float* B = A + NH;
    size_t wpoff = alignup(hoff + 2 * (size_t)NH);
    unsigned short* Wp1 = (unsigned short*)(ws + wpoff);
    unsigned short* Wp2 = Wp1 + 32768;                      // 256*128 bf16
    unsigned short* Wp3 = Wp2 + 16384;                      // 128*128 bf16
    float* odegf = ws + 256 + N;                            // tier C only
    const int* flag = (const int*)meta;

    dim3 blk(256);
    int gN = (N + 255) / 256;
    int gE = (E + 255) / 256;
    int gE2 = (E + 1) / 2;
    int gNH = (NH + 255) / 256;
    int gGemm = (N + 63) / 64;
    int gNode = (N + 3) / 4;

    sniff_dtype<<<1, blk, 0, stream>>>((const unsigned int*)x, (int*)meta);
    compute_jkw<<<1, 64, 0, stream>>>(jkb, meta);

    if (tier < 2) {
        // ---- CSR build (round-3 verbatim) ----
        hipMemsetAsync(cntc, 0, 2 * (size_t)N * 4, stream);
        histo<<<gE, blk, 0, stream>>>(row, col, cntc, cntr, E);
        dinv_from_cnt<<<gN, blk, 0, stream>>>(cntc, dinv, N);
        if (tier == 0) {
            scan2<<<2, 1024, 0, stream>>>(cntc, coff, curc, cntr, roff, curr, N);
            scatter2<<<gE, blk, 0, stream>>>(row, col, curc, curr, ecol, erow, E, 1);
        } else {
            scan2<<<1, 1024, 0, stream>>>(cntc, coff, curc, cntc, coff, curc, N);
            scatter2<<<gE, blk, 0, stream>>>(row, col, curc, curc, ecol, ecol, E, 0);
        }

        // ---- W prepack (dtype-agnostic) ----
        pack_w<<<16, blk, 0, stream>>>(W1, Wp1, flag, 256);
        pack_w<<<8, blk, 0, stream>>>(W2, Wp2, flag, 128);
        pack_w<<<8, blk, 0, stream>>>(W3, Wp3, flag, 128);

        // ---- layer 0: dual self-gating GEMMs (exactly one runs) ----
        gemm128<256, true, true><<<gGemm, blk, 0, stream>>>(x, W1, A, flag, N);          // bf16 world
        gemm_mfma_f32<256, true><<<gGemm, blk, 0, stream>>>((const float*)x, Wp1, A, flag, N); // fp32 world
        agg_gather<<<gNode, blk, 0, stream>>>(coff, ecol, dinv, A, b1, B, flag, N);
        if (tier == 0) {
            mean_gather<<<gNode, blk, 0, stream>>>(roff, erow, B, A, N);
        } else {
            hipMemsetAsync(A, 0, (size_t)NH * 4, stream);
            mean_edges<<<gE2, blk, 0, stream>>>(row, col, B, A, E);
            finalize_mean_cnt<<<gNH, blk, 0, stream>>>(A, B, cntr, A, NH);
        }
        fc_accum<true, false><<<gGemm, blk, 0, stream>>>(A, Wfc, bfc, d_out, meta, 0, N);

        // ---- layer 1: MFMA unconditional (input is fp32 ws buffer) ----
        gemm_mfma_f32<128, false><<<gGemm, blk, 0, stream>>>(A, Wp2, B, flag, N);
        agg_gather<<<gNode, blk, 0, stream>>>(coff, ecol, dinv, B, b2, A, flag, N);
        fc_accum<false, false><<<gGemm, blk, 0, stream>>>(A, Wfc, bfc, d_out, meta, 1, N);

        // ---- layer 2 ----
        gemm_mfma_f32<128, false><<<gGemm, blk, 0, stream>>>(A, Wp3, B, flag, N);
        agg_gather<<<gNode, blk, 0, stream>>>(coff, ecol, dinv, B, b3, A, flag, N);
        fc_accum<false, true><<<gGemm, blk, 0, stream>>>(A, Wfc, bfc, d_out, meta, 2, N);
    } else {
        // ---- tier C: round-3 verbatim (fp32 gemm128, atomic path) ----
        init_deg<<<gN, blk, 0, stream>>>(dinv, odegf, N);
        count_deg<<<gE, blk, 0, stream>>>(row, col, dinv, odegf, E);
        deg_to_dinv<<<gN, blk, 0, stream>>>(dinv, N);

        gemm128<256, true, false><<<gGemm, blk, 0, stream>>>(x, W1, A, flag, N);
        hipMemsetAsync(B, 0, (size_t)NH * 4, stream);
        agg_edges<<<gE2, blk, 0, stream>>>(row, col, dinv, A, B, E);
        finalize_layer<<<gNH, blk, 0, stream>>>(B, A, dinv, b1, B, flag, NH);
        hipMemsetAsync(A, 0, (size_t)NH * 4, stream);
        mean_edges<<<gE2, blk, 0, stream>>>(row, col, B, A, E);
        finalize_mean<<<gNH, blk, 0, stream>>>(A, B, odegf, A, NH);
        fc_accum<true, false><<<gGemm, blk, 0, stream>>>(A, Wfc, bfc, d_out, meta, 0, N);

        gemm128<128, false, false><<<gGemm, blk, 0, stream>>>(A, W2, B, flag, N);
        hipMemsetAsync(A, 0, (size_t)NH * 4, stream);
        agg_edges<<<gE2, blk, 0, stream>>>(row, col, dinv, B, A, E);
        finalize_layer<<<gNH, blk, 0, stream>>>(A, B, dinv, b2, A, flag, NH);
        fc_accum<false, false><<<gGemm, blk, 0, stream>>>(A, Wfc, bfc, d_out, meta, 1, N);

        gemm128<128, false, false><<<gGemm, blk, 0, stream>>>(A, W3, B, flag, N);
        hipMemsetAsync(A, 0, (size_t)NH * 4, stream);
        agg_edges<<<gE2, blk, 0, stream>>>(row, col, dinv, B, A, E);
        finalize_layer<<<gNH, blk, 0, stream>>>(A, B, dinv, b3, A, flag, NH);
        fc_accum<false, true><<<gGemm, blk, 0, stream>>>(A, Wfc, bfc, d_out, meta, 2, N);
    }
}